// Round 13
// baseline (161.028 us; speedup 1.0000x reference)
//
#include <hip/hip_runtime.h>
#include <cstdint>
#include <cstddef>

// ---------------- problem constants ----------------
#define NIMG   8
#define NPROP  2000
#define NCLS   91
#define NFG    90
#define NROW   (NIMG * NPROP)      // 16000
#define TOPK   2048
#define DETS   100
#define CKCAP  32768
#define KREGS  12                  // register-resident keys/thread (fallback radix)
#define NBIN   16384               // score-histogram bins = top 14 bits of 64-bit key
#define TIEK   2048                // max tie-bin size handled by fast select (else radix)

#define IMG_Wf 1333.0f
#define IMG_Hf 800.0f
#define SCORE_TH 0.05f
#define MINSZ    0.01f
#define NMS_TH   0.5f
#define CLIPV    4.135166556742356f   // log(1000/16) rounded to f32
#define ORD_NEG1 0x407FFFFFu          // ford(-1.0f)
#define PADKEY   (((ull)ORD_NEG1 << 32) | 0xFFFFFFFFull)

typedef unsigned long long ull;

// ---------------- workspace layout (bytes) ----------------
static const size_t OFF_CNT = 0;          // 8 counters, 256B apart (2048) — memset region
static const size_t OFF_VBM = 4096;       // 16000*2*8 = 256000
static const size_t OFF_CK  = 262144;     // 8*32768*8 = 2 MiB
#define MEMSET_BYTES 2048

// ---------------- helpers ----------------
__device__ __forceinline__ unsigned ford(float f) {
    unsigned u = __float_as_uint(f);
    return (u & 0x80000000u) ? ~u : (u | 0x80000000u);
}
__device__ __forceinline__ float fordinv(unsigned x) {
    return (x & 0x80000000u) ? __uint_as_float(x & 0x7FFFFFFFu)
                             : __uint_as_float(~x);
}

// exact op-for-op mirror of reference _decode + clip (no FMA contraction)
__device__ __forceinline__ float4 decode_clip(float4 p, float4 r) {
    float w  = __fsub_rn(p.z, p.x);
    float h  = __fsub_rn(p.w, p.y);
    float cx = __fadd_rn(p.x, __fmul_rn(0.5f, w));
    float cy = __fadd_rn(p.y, __fmul_rn(0.5f, h));
    float dx = __fdiv_rn(r.x, 10.0f);
    float dy = __fdiv_rn(r.y, 10.0f);
    float dw = fminf(__fdiv_rn(r.z, 5.0f), CLIPV);
    float dh = fminf(__fdiv_rn(r.w, 5.0f), CLIPV);
    float pcx = __fadd_rn(__fmul_rn(dx, w), cx);
    float pcy = __fadd_rn(__fmul_rn(dy, h), cy);
    float pw  = __fmul_rn(expf(dw), w);
    float ph  = __fmul_rn(expf(dh), h);
    float x1 = __fsub_rn(pcx, __fmul_rn(0.5f, pw));
    float y1 = __fsub_rn(pcy, __fmul_rn(0.5f, ph));
    float x2 = __fadd_rn(pcx, __fmul_rn(0.5f, pw));
    float y2 = __fadd_rn(pcy, __fmul_rn(0.5f, ph));
    float4 o;
    o.x = fminf(fmaxf(x1, 0.0f), IMG_Wf);
    o.y = fminf(fmaxf(y1, 0.0f), IMG_Hf);
    o.z = fminf(fmaxf(x2, 0.0f), IMG_Wf);
    o.w = fminf(fmaxf(y2, 0.0f), IMG_Hf);
    return o;
}

// bitonic wave-local phase with payload: thread owns elements (base, base+1)
__device__ __forceinline__ void wl_pair(ull& a, ull& b, int& pa, int& pb,
                                        int l, int base, int k, int jmax) {
    bool desc = ((base & k) == 0);
    for (int j = jmax; j >= 2; j >>= 1) {
        int pl = l ^ (j >> 1);
        bool lower = ((base & j) == 0);
        ull qa = __shfl(a, pl), qb = __shfl(b, pl);
        int ra = __shfl(pa, pl), rb = __shfl(pb, pl);
        bool km = (desc == lower);
        bool ta = km ? (a > qa) : (a < qa);
        a = ta ? a : qa;  pa = ta ? pa : ra;
        bool tb = km ? (b > qb) : (b < qb);
        b = tb ? b : qb;  pb = tb ? pb : rb;
    }
    bool sw = ((a < b) == desc);
    if (sw) { ull t = a; a = b; b = t; int tp = pa; pa = pb; pb = tp; }
}

// ============ kernel A: softmax + score-gated decode + valid -> keys + bitmap ============
// (unchanged from verified R10 version; no global hist atomics)
__global__ __launch_bounds__(1024) void kA(const float* __restrict__ logits,
                                           const float* __restrict__ reg,
                                           const float* __restrict__ props,
                                           ull* __restrict__ ck,
                                           int* __restrict__ cntv,
                                           ull* __restrict__ vbm2) {
    __shared__ int sCnt16[32], sExc16[32];
    __shared__ int sBase;

    int tid  = threadIdx.x;
    int lane = tid & 63;
    int warp = tid >> 6;

    int row = blockIdx.x * 16 + warp;
    int bA  = row / NPROP;               // uniform within block
    int n   = row - bA * NPROP;
    const float* lrow = logits + (size_t)row * NCLS;

    float xa = lrow[lane];
    float xb = (lane < 27) ? lrow[64 + lane] : -INFINITY;
    float mx = fmaxf(xa, xb);
    #pragma unroll
    for (int o = 32; o; o >>= 1) mx = fmaxf(mx, __shfl_xor(mx, o));
    float ea = expf(__fsub_rn(xa, mx));
    float eb = (lane < 27) ? expf(__fsub_rn(xb, mx)) : 0.0f;
    float sden = __fadd_rn(ea, eb);
    #pragma unroll
    for (int o = 32; o; o >>= 1) sden = __fadd_rn(sden, __shfl_xor(sden, o));

    const float4 p = *reinterpret_cast<const float4*>(props + (size_t)row * 4);

    ull rowmask[2];
    bool validA[2];
    ull keyA[2];
    #pragma unroll
    for (int it = 0; it < 2; ++it) {
        int c = (it == 0) ? (1 + lane) : (65 + lane);
        bool active = (it == 0) ? true : (lane < 26);
        float lg;
        if (it == 0) {
            float s1 = __shfl(xa, (lane + 1) & 63);
            float s2 = __shfl(xb, 0);
            lg = (lane < 63) ? s1 : s2;           // lrow[1+lane]
        } else {
            lg = __shfl(xb, (lane + 1) & 63);     // lrow[65+lane], used for lane<26
        }
        bool valid = false;
        ull key = 0;
        if (active) {
            float score = __fdiv_rn(expf(__fsub_rn(lg, mx)), sden);
            if (score > SCORE_TH) {               // decode only when score passes
                float4 r4 = *reinterpret_cast<const float4*>(
                    reg + ((size_t)row * NCLS + c) * 4);
                float4 bx = decode_clip(p, r4);
                float bw = __fsub_rn(bx.z, bx.x);
                float bh = __fsub_rn(bx.w, bx.y);
                valid = (bw >= MINSZ) && (bh >= MINSZ);
                if (valid) {
                    int offidx = n * NFG + (c - 1);
                    key = ((ull)ford(score) << 32) |
                          (ull)(0xFFFFFFFFu - (unsigned)offidx);
                }
            }
        }
        ull bal = __ballot(valid);
        rowmask[it] = bal;
        validA[it] = valid;
        keyA[it] = key;
        if (lane == 0) sCnt16[warp * 2 + it] = __popcll(bal);
    }
    __syncthreads();
    if (warp == 0) {
        int c = (lane < 32) ? sCnt16[lane] : 0;
        int p2 = c;
        #pragma unroll
        for (int o = 1; o < 32; o <<= 1) {
            int v = __shfl_up(p2, o);
            if (lane >= o) p2 += v;
        }
        if (lane == 31) sBase = atomicAdd(&cntv[bA * 64], p2);
        if (lane < 32) sExc16[lane] = p2 - c;
    }
    __syncthreads();
    int base = sBase;
    #pragma unroll
    for (int it = 0; it < 2; ++it) {
        if (validA[it]) {
            int slot = base + sExc16[warp * 2 + it] +
                       __popcll(rowmask[it] & ((1ull << lane) - 1ull));
            if (slot < CKCAP)
                ck[(size_t)bA * CKCAP + slot] = keyA[it];
        }
    }
    if (lane == 0) {
        vbm2[(size_t)row * 2]     = rowmask[0];
        vbm2[(size_t)row * 2 + 1] = rowmask[1];
    }
}

// ============================================================================
// kernel P: per-image post-process (one block per image, 1024 threads).
// Phase S: LDS-hist top-2048 select (verified in R10 kB)
// Phase D: decode 2048 + class bucketing into LDS (verified R2 P1)
// Phase N: per-class NMS by warp, LDS-resident (verified R2 P2)
// Phase E: two-segment top-100 emit (verified R2 P3)
// LDS arena (84 KB), phase-aliased; every alias transition barrier-separated:
//  [0,16K)    sk (S,D)                | kk (E)
//  [16K,80K)  lhist (S-hist)          | tb/histw/rex (S-select) | clsboxL [16K,48K) (D,N)
//  [56K,72K)  clskeyL (D,N,E)   [72K,74K) keepb (D,N,E)   [74K,82K) ks (E)
// ============================================================================
__global__ __launch_bounds__(1024) void kP(const ull* __restrict__ ck,
                                           const int* __restrict__ cntv,
                                           const ull* __restrict__ vbm2,
                                           const float* __restrict__ reg,
                                           const float* __restrict__ props,
                                           float* __restrict__ out) {
    __shared__ __align__(16) char sArena[83968];
    ull*      sk      = (ull*)sArena;                    // [0,16K)
    ull*      kk      = (ull*)sArena;                    // [0,16K) (E)
    unsigned* lhist   = (unsigned*)(sArena + 16384);     // [16K,80K) 64KB (S-hist)
    ull*      tb      = (ull*)(sArena + 16384);          // [16K,32K) (S-tie)
    unsigned* histw   = (unsigned*)(sArena + 16384);     // [16K,32K) (radix fallbacks)
    int*      rex     = (int*)(sArena + 16384);          // [16K,24K) (fill path)
    float4*   clsboxL = (float4*)(sArena + 16384);       // [16K,48K) (D,N)
    ull*      clskeyL = (ull*)(sArena + 57344);          // [56K,72K)
    unsigned char* keepb = (unsigned char*)(sArena + 73728); // [72K,74K)
    int*      ks      = (int*)(sArena + 75776);          // [74K,82K)

    __shared__ int wsum[16];
    __shared__ int sTot, sT, sRemT, sHt;
    __shared__ int sSel, sTie;
    __shared__ unsigned wtot4[4];
    __shared__ ull sP;
    __shared__ int sRem, sCnt, sDone;
    __shared__ float sM1;
    __shared__ float sMax[16];
    __shared__ int sInv, sVT;
    __shared__ int ccnt[96], cplc[96], coff[96];
    __shared__ int sK, sFC;
    __shared__ ull fkey[128];
    __shared__ int fslot[128];

    int b = blockIdx.x;
    int tid  = threadIdx.x;
    int lane = tid & 63;
    int warp = tid >> 6;

    int cnt = cntv[b * 64];
    const ull* K = ck + (size_t)b * CKCAP;
    int cntS = (cnt > CKCAP) ? CKCAP : cnt;    // stored keys

    // ============ Phase S: LDS hist build + threshold scan ============
    {
        for (int i = tid; i < NBIN; i += 1024) lhist[i] = 0u;
        __syncthreads();
        for (int i = tid; i < cntS; i += 1024)
            atomicAdd(&lhist[(unsigned)(K[i] >> 50)], 1u);
        __syncthreads();

        const uint4* H4 = (const uint4*)lhist;
        uint4 h0 = H4[tid * 4 + 0];
        uint4 h1 = H4[tid * 4 + 1];
        uint4 h2 = H4[tid * 4 + 2];
        uint4 h3 = H4[tid * 4 + 3];
        int L = (int)(h0.x + h0.y + h0.z + h0.w + h1.x + h1.y + h1.z + h1.w +
                      h2.x + h2.y + h2.z + h2.w + h3.x + h3.y + h3.z + h3.w);
        int pfx = L;
        #pragma unroll
        for (int o = 1; o < 64; o <<= 1) {
            int v = __shfl_up(pfx, o);
            if (lane >= o) pfx += v;
        }
        if (lane == 63) wsum[warp] = pfx;
        __syncthreads();
        if (tid == 0) {
            int a = 0;
            for (int w = 0; w < 16; ++w) { int t = wsum[w]; wsum[w] = a; a += t; }
            sTot = a;
        }
        __syncthreads();
        int incl = pfx + wsum[warp];
        int up = sTot - incl;                 // keys in bins owned by higher threads
        if (up < TOPK && up + L >= TOPK) {    // crossing thread (unique)
            unsigned hh[16] = {h0.x, h0.y, h0.z, h0.w, h1.x, h1.y, h1.z, h1.w,
                               h2.x, h2.y, h2.z, h2.w, h3.x, h3.y, h3.z, h3.w};
            int c = up; int tf = 0; int Sv = 0; unsigned htv = 0; int fnd = 0;
            #pragma unroll
            for (int j = 15; j >= 0; --j) {
                int nc = c + (int)hh[j];
                if (!fnd && nc >= TOPK) { tf = j; Sv = c; htv = hh[j]; fnd = 1; }
                c = nc;
            }
            sT = tid * 16 + tf;
            sRemT = TOPK - Sv;
            sHt = (int)htv;
        }
    }
    __syncthreads();

    bool needRadix = false;
    if (cnt >= TOPK && cnt <= CKCAP) {
        int thr = sT, rem = sRemT, ht = sHt;
        if (ht <= TIEK) {
            // ---- fast exact select: one pass + tie-rank ----
            if (tid == 0) { sSel = 0; sTie = 0; }
            __syncthreads();
            for (int i = tid; i < cnt; i += 1024) {
                ull k2 = K[i];
                int bin = (int)(unsigned)(k2 >> 50);
                bool sel = bin > thr;
                bool tie = bin == thr;
                ull bal = __ballot(sel);
                int cw = __popcll(bal);
                if (cw) {
                    int ldr = __ffsll((long long)bal) - 1;
                    int bw = 0;
                    if (lane == ldr) bw = atomicAdd(&sSel, cw);
                    bw = __shfl(bw, ldr);
                    if (sel) sk[bw + __popcll(bal & ((1ull << lane) - 1ull))] = k2;
                }
                ull bal2 = __ballot(tie);
                int cw2 = __popcll(bal2);
                if (cw2) {
                    int ldr = __ffsll((long long)bal2) - 1;
                    int bw = 0;
                    if (lane == ldr) bw = atomicAdd(&sTie, cw2);
                    bw = __shfl(bw, ldr);
                    if (tie) tb[bw + __popcll(bal2 & ((1ull << lane) - 1ull))] = k2;
                }
            }
            __syncthreads();
            int tieCnt = sTie;                 // == ht
            for (int i = tid; i < tieCnt; i += 1024) {
                ull me = tb[i];
                int rank = 0;
                for (int j = 0; j < tieCnt; ++j) rank += (tb[j] > me);
                if (rank < rem) { int pos = atomicAdd(&sSel, 1); sk[pos] = me; }
            }
            __syncthreads();                   // sk[0..TOPK) complete
        } else {
            needRadix = true;                  // giant tie bin: unreachable
        }
    } else if (cnt >= TOPK) {
        needRadix = true;                      // cnt > CKCAP: unreachable
    }

    if (needRadix) {
        // ---- fallback: 8x8-bit radix select (proven, statically unreachable) ----
        int cntc = (cnt > CKCAP) ? CKCAP : cnt;
        ull kreg[KREGS];
        #pragma unroll
        for (int r = 0; r < KREGS; ++r) {
            int i = tid + (r << 10);
            kreg[r] = (i < cntc) ? K[i] : 0ull;
        }
        ull P = 0; int rem = TOPK;
        for (int pass = 7; pass >= 0; --pass) {
            int sh = pass * 8;
            *reinterpret_cast<uint4*>(&histw[tid * 4]) = make_uint4(0, 0, 0, 0);
            __syncthreads();
            ull pmask = (pass == 7) ? 0ull : (~0ull << (sh + 8));
            unsigned* hw = &histw[warp << 8];
            #pragma unroll
            for (int r = 0; r < KREGS; ++r) {
                int i = tid + (r << 10);
                if (i < cntc && (kreg[r] & pmask) == P)
                    atomicAdd(&hw[(unsigned)(kreg[r] >> sh) & 255u], 1u);
            }
            for (int i = (KREGS << 10) + tid; i < cntc; i += 1024) {
                ull k2 = K[i];
                if ((k2 & pmask) == P)
                    atomicAdd(&hw[(unsigned)(k2 >> sh) & 255u], 1u);
            }
            __syncthreads();
            unsigned x = 0, pfx2 = 0;
            if (tid < 256) {
                int d = 255 - tid;
                #pragma unroll
                for (int w = 0; w < 16; ++w) x += histw[(w << 8) + d];
                pfx2 = x;
                #pragma unroll
                for (int o = 1; o < 64; o <<= 1) {
                    unsigned v = __shfl_up(pfx2, o);
                    if (lane >= o) pfx2 += v;
                }
                if (lane == 63) wtot4[tid >> 6] = pfx2;
            }
            __syncthreads();
            if (tid < 256) {
                int d = 255 - tid;
                int ws2 = tid >> 6;
                unsigned add = 0;
                if (ws2 > 0) add += wtot4[0];
                if (ws2 > 1) add += wtot4[1];
                if (ws2 > 2) add += wtot4[2];
                unsigned pi   = pfx2 + add;
                unsigned excl = pi - x;
                if (x && excl < (unsigned)rem && pi >= (unsigned)rem) {
                    sP = P | ((ull)(unsigned)d << sh);
                    int nr = rem - (int)excl;
                    sRem = nr;
                    sDone = ((int)x == nr) ? 1 : 0;
                }
            }
            __syncthreads();
            P = sP; rem = sRem;
            if (sDone) break;
        }
        if (tid == 0) sCnt = 0;
        __syncthreads();
        #pragma unroll
        for (int r = 0; r < KREGS; ++r) {
            int i = tid + (r << 10);
            bool sel = (i < cntc) && (kreg[r] >= P);
            ull bal = __ballot(sel);
            int cw = __popcll(bal);
            if (cw) {
                int ldr = __ffsll((long long)bal) - 1;
                int bw = 0;
                if (lane == ldr) bw = atomicAdd(&sCnt, cw);
                bw = __shfl(bw, ldr);
                if (sel) {
                    int pos = bw + __popcll(bal & ((1ull << lane) - 1ull));
                    if (pos < TOPK) sk[pos] = kreg[r];
                }
            }
        }
        for (int i = (KREGS << 10) + tid; i < cntc; i += 1024) {
            ull k2 = K[i];
            bool sel = (k2 >= P);
            ull bal = __ballot(sel);
            int cw = __popcll(bal);
            if (cw) {
                int ldr = __ffsll((long long)bal) - 1;
                int bw = 0;
                if (lane == ldr) bw = atomicAdd(&sCnt, cw);
                bw = __shfl(bw, ldr);
                if (sel) {
                    int pos = bw + __popcll(bal & ((1ull << lane) - 1ull));
                    if (pos < TOPK) sk[pos] = k2;
                }
            }
        }
        __syncthreads();
        int fc = sCnt;
        for (int i = fc + tid; i < TOPK; i += 1024) sk[i] = PADKEY;
        __syncthreads();
    } else if (cnt < TOPK) {
        // ---- take all valid + fill with smallest-index invalid (unreachable) ----
        for (int i = tid; i < cnt; i += 1024) sk[i] = K[i];
        int F = TOPK - cnt;
        const ull* V = vbm2 + (size_t)b * NPROP * 2;
        int r0 = 2 * tid, r1 = r0 + 1;
        int v0 = 0, v1 = 0;
        if (r0 < NPROP) v0 = NFG - __popcll(V[r0 * 2]) - __popcll(V[r0 * 2 + 1]);
        if (r1 < NPROP) v1 = NFG - __popcll(V[r1 * 2]) - __popcll(V[r1 * 2 + 1]);
        int s2 = v0 + v1;
        int pfx = s2;
        #pragma unroll
        for (int o = 1; o < 64; o <<= 1) {
            int t = __shfl_up(pfx, o);
            if (lane >= o) pfx += t;
        }
        if (lane == 63) wsum[warp] = pfx;
        __syncthreads();
        if (tid == 0) {
            int a = 0;
            for (int w = 0; w < 16; ++w) { int t = wsum[w]; wsum[w] = a; a += t; }
        }
        __syncthreads();
        int excl = pfx - s2 + wsum[warp];
        if (r0 < NPROP) rex[r0] = excl;
        if (r1 < NPROP) rex[r1] = excl + v0;
        __syncthreads();
        for (int r = tid; r < NPROP; r += 1024) {
            int e = rex[r];
            if (e < F) {
                ull m0 = V[r * 2], m1v = V[r * 2 + 1];
                int rank = e;
                ull inv = ~m0;
                while (inv && rank < F) {
                    int cb = __builtin_ctzll(inv); inv &= inv - 1;
                    unsigned idx = (unsigned)(r * NFG + cb);
                    sk[cnt + rank] = ((ull)ORD_NEG1 << 32) | (ull)(0xFFFFFFFFu - idx);
                    ++rank;
                }
                inv = (~m1v) & ((1ull << 26) - 1ull);
                while (inv && rank < F) {
                    int cb = __builtin_ctzll(inv); inv &= inv - 1;
                    unsigned idx = (unsigned)(r * NFG + 64 + cb);
                    sk[cnt + rank] = ((ull)ORD_NEG1 << 32) | (ull)(0xFFFFFFFFu - idx);
                    ++rank;
                }
            }
        }
        __syncthreads();
    }

    // ============ Phase D: decode 2048 + class bucketing into LDS ============
    float lmax = 0.0f;
    float4 myb[2]; int myl[2]; bool vk2[2]; ull kk2[2];
    #pragma unroll
    for (int r = 0; r < 2; ++r) {
        int pos0 = tid + (r << 10);
        ull k = sk[pos0];
        unsigned idx = 0xFFFFFFFFu - (unsigned)(k & 0xFFFFFFFFu);
        int n2 = (int)(idx / NFG), c2 = (int)(idx % NFG);  // label = c2+1
        int row2 = b * NPROP + n2;
        float4 p  = *reinterpret_cast<const float4*>(props + (size_t)row2 * 4);
        float4 r4 = *reinterpret_cast<const float4*>(
            reg + ((size_t)row2 * NCLS + (c2 + 1)) * 4);
        float4 bxv = decode_clip(p, r4);
        myb[r] = bxv; myl[r] = c2 + 1; kk2[r] = k;
        vk2[r] = (((unsigned)(k >> 32)) != ORD_NEG1);
        lmax = fmaxf(lmax, fmaxf(fmaxf(bxv.x, bxv.y), fmaxf(bxv.z, bxv.w)));
    }
    #pragma unroll
    for (int o = 32; o; o >>= 1) lmax = fmaxf(lmax, __shfl_xor(lmax, o));
    if (lane == 0) sMax[warp] = lmax;
    if (tid < 96) { ccnt[tid] = 0; cplc[tid] = 0; }
    if (tid == 0) sInv = 0;
    keepb[tid] = 0; keepb[tid + 1024] = 0;
    __syncthreads();
    if (tid == 0) {
        float v = sMax[0];
        for (int i = 1; i < 16; ++i) v = fmaxf(v, sMax[i]);
        sM1 = __fadd_rn(v, 1.0f);            // jnp.max(cand_boxes) + 1.0
    }
    #pragma unroll
    for (int r = 0; r < 2; ++r)
        if (vk2[r]) atomicAdd(&ccnt[myl[r] - 1], 1);
    __syncthreads();
    if (tid == 0) {
        int a = 0;
        for (int c2 = 0; c2 < NFG; ++c2) { coff[c2] = a; a += ccnt[c2]; }
        sVT = a;
    }
    __syncthreads();
    float m1 = sM1;
    int validTot = sVT;
    #pragma unroll
    for (int r = 0; r < 2; ++r) {
        int slot;
        if (vk2[r]) {
            int cl = myl[r] - 1;
            slot = coff[cl] + atomicAdd(&cplc[cl], 1);
        } else {
            slot = validTot + atomicAdd(&sInv, 1);
        }
        float off = __fmul_rn((float)myl[r], m1);
        float4 ob;
        ob.x = __fadd_rn(myb[r].x, off);
        ob.y = __fadd_rn(myb[r].y, off);
        ob.z = __fadd_rn(myb[r].z, off);
        ob.w = __fadd_rn(myb[r].w, off);
        clsboxL[slot] = ob;            // overlays tb/histw (dead); sk untouched
        clskeyL[slot] = kk2[r];
    }
    __syncthreads();

    // ============ Phase N: per-class key-sort + greedy NMS (wave-local) ============
    {
        for (int cls = warp; cls < NFG; cls += 16) {
            int n = ccnt[cls];
            if (n <= 0) continue;
            int base2 = coff[cls];
            if (n <= 64) {
                ull key = (lane < n) ? clskeyL[base2 + lane] : (ull)lane;
                int pos = (lane < n) ? (base2 + lane) : -1;
                #pragma unroll
                for (int k2 = 2; k2 <= 64; k2 <<= 1) {
                    #pragma unroll
                    for (int j = k2 >> 1; j > 0; j >>= 1) {
                        int pl = lane ^ j;
                        ull qk = __shfl(key, pl);
                        int qs = __shfl(pos, pl);
                        bool desc = ((lane & k2) == 0);
                        bool lower = ((lane & j) == 0);
                        bool km = (desc == lower);
                        bool keepown = km ? (key > qk) : (key < qk);
                        key = keepown ? key : qk;
                        pos = keepown ? pos : qs;
                    }
                }
                float4 b0 = make_float4(0.f, 0.f, 0.f, 0.f);
                float a0 = 0.0f;
                if (pos >= 0) {
                    b0 = clsboxL[pos];
                    a0 = __fmul_rn(__fsub_rn(b0.z, b0.x), __fsub_rn(b0.w, b0.y));
                }
                ull alive = (n == 64) ? ~0ull : ((1ull << n) - 1ull);
                #pragma unroll 1
                for (int i = 0; i < n; ++i) {
                    if (!((alive >> i) & 1ull)) continue;
                    float bix = __shfl(b0.x, i), biy = __shfl(b0.y, i);
                    float biz = __shfl(b0.z, i), biw = __shfl(b0.w, i);
                    float ai2 = __shfl(a0, i);
                    bool sup = false;
                    if (lane < n && lane > i) {
                        float lt0 = fmaxf(bix, b0.x), lt1 = fmaxf(biy, b0.y);
                        float rb0 = fminf(biz, b0.z), rb1 = fminf(biw, b0.w);
                        float w0 = fmaxf(__fsub_rn(rb0, lt0), 0.0f);
                        float w1 = fmaxf(__fsub_rn(rb1, lt1), 0.0f);
                        float inter = __fmul_rn(w0, w1);
                        if (inter > 0.0f) {
                            float un = __fsub_rn(__fadd_rn(ai2, a0), inter);
                            sup = (__fdiv_rn(inter, un) > NMS_TH);
                        }
                    }
                    alive &= ~__ballot(sup);
                }
                if (lane < n) keepb[pos] = (unsigned char)((alive >> lane) & 1ull);
            } else {
                // barrier-free cold path (statistically unreachable):
                // greedy in key-desc order via argmax chain; per-lane alive bits.
                unsigned aliveLoc = 0;
                #pragma unroll 1
                for (int k2 = 0; k2 < 32; ++k2) {
                    int j = (k2 << 6) + lane;
                    if (j < n) aliveLoc |= (1u << k2);
                }
                ull prevKey = ~0ull;
                while (true) {
                    ull bk = 0; int bp = -1;
                    #pragma unroll 1
                    for (int k2 = 0; k2 < 32; ++k2) {
                        if ((aliveLoc >> k2) & 1u) {
                            int j = (k2 << 6) + lane;
                            ull kj = clskeyL[base2 + j];
                            if (kj < prevKey && kj > bk) { bk = kj; bp = j; }
                        }
                    }
                    #pragma unroll
                    for (int o = 32; o; o >>= 1) {
                        ull ok = __shfl_xor(bk, o);
                        int op = __shfl_xor(bp, o);
                        if (ok > bk) { bk = ok; bp = op; }
                    }
                    if (bp < 0) break;
                    float4 bi = clsboxL[base2 + bp];
                    float ai = __fmul_rn(__fsub_rn(bi.z, bi.x), __fsub_rn(bi.w, bi.y));
                    #pragma unroll 1
                    for (int k2 = 0; k2 < 32; ++k2) {
                        if ((aliveLoc >> k2) & 1u) {
                            int j = (k2 << 6) + lane;
                            ull kj = clskeyL[base2 + j];
                            if (kj < bk) {
                                float4 bj = clsboxL[base2 + j];
                                float aj = __fmul_rn(__fsub_rn(bj.z, bj.x),
                                                     __fsub_rn(bj.w, bj.y));
                                float lt0 = fmaxf(bi.x, bj.x), lt1 = fmaxf(bi.y, bj.y);
                                float rb0 = fminf(bi.z, bj.z), rb1 = fminf(bi.w, bj.w);
                                float w0 = fmaxf(__fsub_rn(rb0, lt0), 0.0f);
                                float w1 = fmaxf(__fsub_rn(rb1, lt1), 0.0f);
                                float inter = __fmul_rn(w0, w1);
                                if (inter > 0.0f) {
                                    float un = __fsub_rn(__fadd_rn(ai, aj), inter);
                                    if (__fdiv_rn(inter, un) > NMS_TH)
                                        aliveLoc &= ~(1u << k2);
                                }
                            }
                        }
                    }
                    prevKey = bk;
                }
                #pragma unroll 1
                for (int k2 = 0; k2 < 32; ++k2) {
                    int j = (k2 << 6) + lane;
                    if (j < n) keepb[base2 + j] = (unsigned char)((aliveLoc >> k2) & 1u);
                }
            }
        }
    }
    __syncthreads();

    // ============ Phase E: two-segment top-100 selection + emit ============
    {
        int emitted = 0;
        #pragma unroll 1
        for (int seg = 0; seg < 2; ++seg) {
            __syncthreads();
            if (tid == 0) sK = 0;
            __syncthreads();
            if (emitted < DETS) {
                for (int s = tid; s < TOPK; s += 1024) {
                    bool f = (seg == 0) ? (keepb[s] != 0) : (keepb[s] == 0);
                    ull key = clskeyL[s];
                    ull bal = __ballot(f);
                    int cw = __popcll(bal);
                    if (cw) {
                        int ldr = __ffsll((long long)bal) - 1;
                        int bw = 0;
                        if (lane == ldr) bw = atomicAdd(&sK, cw);
                        bw = __shfl(bw, ldr);
                        if (f) {
                            int p2 = bw + __popcll(bal & ((1ull << lane) - 1ull));
                            kk[p2] = key; ks[p2] = s;     // kk overlays sk (dead)
                        }
                    }
                }
            }
            __syncthreads();
            int K2 = sK;
            int T = DETS - emitted;
            if (T > K2) T = K2;
            if (emitted < DETS && K2 > 0) {
                ull P = 0;
                if (K2 > T) {
                    int rem = T;
                    for (int pass = 7; pass >= 0; --pass) {
                        int sh = pass * 8;
                        *reinterpret_cast<uint4*>(&histw[tid * 4]) = make_uint4(0, 0, 0, 0);
                        __syncthreads();
                        ull pmask = (pass == 7) ? 0ull : (~0ull << (sh + 8));
                        unsigned* hw = &histw[warp << 8];
                        for (int i = tid; i < K2; i += 1024) {
                            ull k2 = kk[i];
                            if ((k2 & pmask) == P)
                                atomicAdd(&hw[(unsigned)(k2 >> sh) & 255u], 1u);
                        }
                        __syncthreads();
                        unsigned x = 0, pfx = 0;
                        if (tid < 256) {
                            int d = 255 - tid;
                            #pragma unroll
                            for (int w = 0; w < 16; ++w) x += histw[(w << 8) + d];
                            pfx = x;
                            #pragma unroll
                            for (int o = 1; o < 64; o <<= 1) {
                                unsigned v = __shfl_up(pfx, o);
                                if (lane >= o) pfx += v;
                            }
                            if (lane == 63) wtot4[tid >> 6] = pfx;
                        }
                        __syncthreads();
                        if (tid < 256) {
                            int d = 255 - tid;
                            int ws2 = tid >> 6;
                            unsigned add = 0;
                            if (ws2 > 0) add += wtot4[0];
                            if (ws2 > 1) add += wtot4[1];
                            if (ws2 > 2) add += wtot4[2];
                            unsigned pi   = pfx + add;
                            unsigned excl = pi - x;
                            if (x && excl < (unsigned)rem && pi >= (unsigned)rem) {
                                sP = P | ((ull)(unsigned)d << sh);
                                int nr = rem - (int)excl;
                                sRem = nr;
                                sDone = ((int)x == nr) ? 1 : 0;
                            }
                        }
                        __syncthreads();
                        P = sP; rem = sRem;
                        if (sDone) break;
                    }
                }
                if (tid == 0) sFC = 0;
                __syncthreads();
                for (int i = tid; i < K2; i += 1024) {
                    ull k2 = kk[i];
                    bool sel = (k2 >= P);
                    ull bal = __ballot(sel);
                    int cw = __popcll(bal);
                    if (cw) {
                        int ldr = __ffsll((long long)bal) - 1;
                        int bw = 0;
                        if (lane == ldr) bw = atomicAdd(&sFC, cw);
                        bw = __shfl(bw, ldr);
                        if (sel) {
                            int p2 = bw + __popcll(bal & ((1ull << lane) - 1ull));
                            if (p2 < T) { fkey[p2] = k2; fslot[p2] = ks[i]; }
                        }
                    }
                }
                __syncthreads();
                int FC = sFC; if (FC > T) FC = T;
                for (int i = FC + tid; i < 128; i += 1024) { fkey[i] = 0; fslot[i] = -1; }
                __syncthreads();
                if (warp == 0) {
                    int base2 = lane * 2;
                    ull a = fkey[base2], bb = fkey[base2 + 1];
                    int pa = fslot[base2], pb = fslot[base2 + 1];
                    #pragma unroll
                    for (int k2 = 2; k2 <= 128; k2 <<= 1)
                        wl_pair(a, bb, pa, pb, lane, base2, k2,
                                (k2 >> 1) < 64 ? (k2 >> 1) : 64);
                    #pragma unroll
                    for (int e = 0; e < 2; ++e) {
                        int rnk = base2 + e;
                        ull kv = e ? bb : a;
                        int sl = e ? pb : pa;
                        if (rnk < T && sl >= 0) {
                            int r2 = emitted + rnk;
                            // re-decode winning box from its key (bit-identical ops)
                            unsigned idx = 0xFFFFFFFFu - (unsigned)(kv & 0xFFFFFFFFu);
                            int n2 = (int)(idx / NFG), c2 = (int)(idx % NFG);
                            int row2 = b * NPROP + n2;
                            float4 pp = *reinterpret_cast<const float4*>(
                                props + (size_t)row2 * 4);
                            float4 r4 = *reinterpret_cast<const float4*>(
                                reg + ((size_t)row2 * NCLS + (c2 + 1)) * 4);
                            float4 bx = decode_clip(pp, r4);
                            *reinterpret_cast<float4*>(
                                out + ((size_t)b * DETS + r2) * 4) = bx;
                            out[NIMG * DETS * 4 + b * DETS + r2] =
                                (seg == 0) ? fordinv((unsigned)(kv >> 32)) : -1.0f;
                            out[NIMG * DETS * 5 + b * DETS + r2] = (float)(c2 + 1);
                        }
                    }
                }
                emitted += T;
            }
            __syncthreads();
        }
    }
}

// ---------------- launch ----------------
extern "C" void kernel_launch(void* const* d_in, const int* in_sizes, int n_in,
                              void* d_out, int out_size, void* d_ws, size_t ws_size,
                              hipStream_t stream) {
    (void)in_sizes; (void)n_in; (void)out_size; (void)ws_size;
    const float* logits = (const float*)d_in[0];   // [16000, 91]
    const float* reg    = (const float*)d_in[1];   // [16000, 364]
    const float* props  = (const float*)d_in[2];   // [8, 2000, 4]
    float* out = (float*)d_out;                    // boxes(3200) | scores(800) | labels(800)
    char* ws = (char*)d_ws;

    int* cntv = (int*)(ws + OFF_CNT);
    ull* vbm2 = (ull*)(ws + OFF_VBM);
    ull* ck   = (ull*)(ws + OFF_CK);

    hipMemsetAsync(ws, 0, MEMSET_BYTES, stream);   // cntv only
    hipLaunchKernelGGL(kA, dim3(NROW / 16), dim3(1024), 0, stream,
                       logits, reg, props, ck, cntv, vbm2);
    hipLaunchKernelGGL(kP, dim3(NIMG), dim3(1024), 0, stream,
                       ck, cntv, vbm2, reg, props, out);
}

// Round 15
// 122.107 us; speedup vs baseline: 1.3187x; 1.3187x over previous
//
#include <hip/hip_runtime.h>
#include <cstdint>
#include <cstddef>

// ---------------- problem constants ----------------
#define NIMG   8
#define NPROP  2000
#define NCLS   91
#define NFG    90
#define NROW   (NIMG * NPROP)      // 16000
#define TOPK   2048
#define DETS   100
#define CKCAP  32768
#define KREGS  12                  // register-resident keys/thread
#define NBIN   16384               // score-histogram bins = top 14 bits of 64-bit key
#define TIEK   2048                // max tie-bin size handled by fast select (else radix)
#define TIEE   256                 // max tie-bin size in kE fast path
#define CLSCAP 512                 // max candidates per (image,class) in kN cold path

#define IMG_Wf 1333.0f
#define IMG_Hf 800.0f
#define SCORE_TH 0.05f
#define MINSZ    0.01f
#define NMS_TH   0.5f
#define CLIPV    4.135166556742356f   // log(1000/16) rounded to f32
#define ORD_NEG1 0x407FFFFFu          // ford(-1.0f)
#define PADKEY   (((ull)ORD_NEG1 << 32) | 0xFFFFFFFFull)

typedef unsigned long long ull;

// ---------------- workspace layout (bytes) ----------------
// memset region [0, 528384): cntv counters + (gap) + per-image kept-histograms
// (hist is written ONLY by kN -> read by kE; kA/kB don't touch it)
static const size_t OFF_CNT    = 0;         // 8 counters, 256B apart    (2048)
static const size_t OFF_HIST   = 4096;      // 8*16384*4 = 524288
static const size_t OFF_VBM    = 528384;    // 16000*2*8 = 256000
static const size_t OFF_CK     = 784384;    // 8*32768*8 = 2097152
static const size_t OFF_CLSBOX = 2881536;   // 8*2048*16 = 262144
static const size_t OFF_CLSAR  = 3143680;   // 8*2048*4  = 65536
static const size_t OFF_CLSKEY = 3209216;   // 8*2048*8  = 131072
static const size_t OFF_KEEPF  = 3340288;   // 8*2048*4  = 65536
static const size_t OFF_CLSCNT = 3405824;   // 8*96*4    = 3072
static const size_t OFF_CLSOFF = 3408896;   // 8*96*4    = 3072
#define MEMSET_BYTES 528384

// ---------------- helpers ----------------
__device__ __forceinline__ unsigned ford(float f) {
    unsigned u = __float_as_uint(f);
    return (u & 0x80000000u) ? ~u : (u | 0x80000000u);
}
__device__ __forceinline__ float fordinv(unsigned x) {
    return (x & 0x80000000u) ? __uint_as_float(x & 0x7FFFFFFFu)
                             : __uint_as_float(~x);
}

// exact op-for-op mirror of reference _decode + clip (no FMA contraction)
__device__ __forceinline__ float4 decode_clip(float4 p, float4 r) {
    float w  = __fsub_rn(p.z, p.x);
    float h  = __fsub_rn(p.w, p.y);
    float cx = __fadd_rn(p.x, __fmul_rn(0.5f, w));
    float cy = __fadd_rn(p.y, __fmul_rn(0.5f, h));
    float dx = __fdiv_rn(r.x, 10.0f);
    float dy = __fdiv_rn(r.y, 10.0f);
    float dw = fminf(__fdiv_rn(r.z, 5.0f), CLIPV);
    float dh = fminf(__fdiv_rn(r.w, 5.0f), CLIPV);
    float pcx = __fadd_rn(__fmul_rn(dx, w), cx);
    float pcy = __fadd_rn(__fmul_rn(dy, h), cy);
    float pw  = __fmul_rn(expf(dw), w);
    float ph  = __fmul_rn(expf(dh), h);
    float x1 = __fsub_rn(pcx, __fmul_rn(0.5f, pw));
    float y1 = __fsub_rn(pcy, __fmul_rn(0.5f, ph));
    float x2 = __fadd_rn(pcx, __fmul_rn(0.5f, pw));
    float y2 = __fadd_rn(pcy, __fmul_rn(0.5f, ph));
    float4 o;
    o.x = fminf(fmaxf(x1, 0.0f), IMG_Wf);
    o.y = fminf(fmaxf(y1, 0.0f), IMG_Hf);
    o.z = fminf(fmaxf(x2, 0.0f), IMG_Wf);
    o.w = fminf(fmaxf(y2, 0.0f), IMG_Hf);
    return o;
}

// bitonic wave-local phase with payload: thread owns elements (base, base+1)
__device__ __forceinline__ void wl_pair(ull& a, ull& b, int& pa, int& pb,
                                        int l, int base, int k, int jmax) {
    bool desc = ((base & k) == 0);
    for (int j = jmax; j >= 2; j >>= 1) {
        int pl = l ^ (j >> 1);
        bool lower = ((base & j) == 0);
        ull qa = __shfl(a, pl), qb = __shfl(b, pl);
        int ra = __shfl(pa, pl), rb = __shfl(pb, pl);
        bool km = (desc == lower);
        bool ta = km ? (a > qa) : (a < qa);
        a = ta ? a : qa;  pa = ta ? pa : ra;
        bool tb = km ? (b > qb) : (b < qb);
        b = tb ? b : qb;  pb = tb ? pb : rb;
    }
    bool sw = ((a < b) == desc);
    if (sw) { ull t = a; a = b; b = t; int tp = pa; pa = pb; pb = tp; }
}

// ============ kernel A: softmax + score-gated decode + valid -> keys + bitmap ============
// (verified R10 version; no global hist atomics)
__global__ __launch_bounds__(1024) void kA(const float* __restrict__ logits,
                                           const float* __restrict__ reg,
                                           const float* __restrict__ props,
                                           ull* __restrict__ ck,
                                           int* __restrict__ cntv,
                                           ull* __restrict__ vbm2) {
    __shared__ int sCnt16[32], sExc16[32];
    __shared__ int sBase;

    int tid  = threadIdx.x;
    int lane = tid & 63;
    int warp = tid >> 6;

    int row = blockIdx.x * 16 + warp;
    int bA  = row / NPROP;               // uniform within block
    int n   = row - bA * NPROP;
    const float* lrow = logits + (size_t)row * NCLS;

    float xa = lrow[lane];
    float xb = (lane < 27) ? lrow[64 + lane] : -INFINITY;
    float mx = fmaxf(xa, xb);
    #pragma unroll
    for (int o = 32; o; o >>= 1) mx = fmaxf(mx, __shfl_xor(mx, o));
    float ea = expf(__fsub_rn(xa, mx));
    float eb = (lane < 27) ? expf(__fsub_rn(xb, mx)) : 0.0f;
    float sden = __fadd_rn(ea, eb);
    #pragma unroll
    for (int o = 32; o; o >>= 1) sden = __fadd_rn(sden, __shfl_xor(sden, o));

    const float4 p = *reinterpret_cast<const float4*>(props + (size_t)row * 4);

    ull rowmask[2];
    bool validA[2];
    ull keyA[2];
    #pragma unroll
    for (int it = 0; it < 2; ++it) {
        int c = (it == 0) ? (1 + lane) : (65 + lane);
        bool active = (it == 0) ? true : (lane < 26);
        float lg;
        if (it == 0) {
            float s1 = __shfl(xa, (lane + 1) & 63);
            float s2 = __shfl(xb, 0);
            lg = (lane < 63) ? s1 : s2;           // lrow[1+lane]
        } else {
            lg = __shfl(xb, (lane + 1) & 63);     // lrow[65+lane], used for lane<26
        }
        bool valid = false;
        ull key = 0;
        if (active) {
            float score = __fdiv_rn(expf(__fsub_rn(lg, mx)), sden);
            if (score > SCORE_TH) {               // decode only when score passes
                float4 r4 = *reinterpret_cast<const float4*>(
                    reg + ((size_t)row * NCLS + c) * 4);
                float4 bx = decode_clip(p, r4);
                float bw = __fsub_rn(bx.z, bx.x);
                float bh = __fsub_rn(bx.w, bx.y);
                valid = (bw >= MINSZ) && (bh >= MINSZ);
                if (valid) {
                    int offidx = n * NFG + (c - 1);
                    key = ((ull)ford(score) << 32) |
                          (ull)(0xFFFFFFFFu - (unsigned)offidx);
                }
            }
        }
        ull bal = __ballot(valid);
        rowmask[it] = bal;
        validA[it] = valid;
        keyA[it] = key;
        if (lane == 0) sCnt16[warp * 2 + it] = __popcll(bal);
    }
    __syncthreads();
    if (warp == 0) {
        int c = (lane < 32) ? sCnt16[lane] : 0;
        int p2 = c;
        #pragma unroll
        for (int o = 1; o < 32; o <<= 1) {
            int v = __shfl_up(p2, o);
            if (lane >= o) p2 += v;
        }
        if (lane == 31) sBase = atomicAdd(&cntv[bA * 64], p2);
        if (lane < 32) sExc16[lane] = p2 - c;
    }
    __syncthreads();
    int base = sBase;
    #pragma unroll
    for (int it = 0; it < 2; ++it) {
        if (validA[it]) {
            int slot = base + sExc16[warp * 2 + it] +
                       __popcll(rowmask[it] & ((1ull << lane) - 1ull));
            if (slot < CKCAP)
                ck[(size_t)bA * CKCAP + slot] = keyA[it];
        }
    }
    if (lane == 0) {
        vbm2[(size_t)row * 2]     = rowmask[0];
        vbm2[(size_t)row * 2 + 1] = rowmask[1];
    }
}

// ============ kernel B: register-cached LDS-hist top-2048 + decode + class bucketing ============
// Keys loaded ONCE into kreg[12] (coalesced); hist build and select/tie
// compaction run from registers (rare >12288 tail from global).
__global__ __launch_bounds__(1024) void kB(const ull* __restrict__ ck,
                                           const int* __restrict__ cntv,
                                           const ull* __restrict__ vbm2,
                                           const float* __restrict__ reg,
                                           const float* __restrict__ props,
                                           float4* __restrict__ clsbox,
                                           float* __restrict__ clsarea,
                                           ull* __restrict__ clskey,
                                           int* __restrict__ keepflag,
                                           int* __restrict__ clscnt,
                                           int* __restrict__ clsoff) {
    // LDS arena: [0,16K) sk keys; [16K,32K) tie-buffer | fallback-radix histw | fill-path rex
    __shared__ __align__(16) char sArena[32768];
    ull*      sk    = (ull*)sArena;
    ull*      tb    = (ull*)(sArena + 16384);
    unsigned* histw = (unsigned*)(sArena + 16384);
    int*      rex   = (int*)(sArena + 16384);
    __shared__ __align__(16) unsigned lhist[NBIN];   // 64 KB LDS histogram

    __shared__ int wsum[16];
    __shared__ int sTot, sT, sRemT, sHt;
    __shared__ int sSel, sTie;
    __shared__ unsigned wtot4[4];
    __shared__ ull sP;
    __shared__ int sRem, sCnt, sDone;
    __shared__ float sM1;
    __shared__ float sMax[16];
    __shared__ int sInv, sVT;
    __shared__ int ccnt[96], cplc[96], coff[96];

    int b = blockIdx.x;
    int tid  = threadIdx.x;
    int lane = tid & 63;
    int warp = tid >> 6;

    int cnt = cntv[b * 64];
    const ull* K = ck + (size_t)b * CKCAP;
    int cntS = (cnt > CKCAP) ? CKCAP : cnt;    // stored keys

    // ---- load keys into registers ONCE (coalesced) ----
    ull kreg[KREGS];
    #pragma unroll
    for (int r = 0; r < KREGS; ++r) {
        int i = tid + (r << 10);
        kreg[r] = (i < cntS) ? K[i] : 0ull;
    }

    // ---- build LDS histogram (from registers), then scan: total + threshold bin ----
    {
        for (int i = tid; i < NBIN; i += 1024) lhist[i] = 0u;
        __syncthreads();
        #pragma unroll
        for (int r = 0; r < KREGS; ++r) {
            int i = tid + (r << 10);
            if (i < cntS)
                atomicAdd(&lhist[(unsigned)(kreg[r] >> 50)], 1u);
        }
        for (int i = (KREGS << 10) + tid; i < cntS; i += 1024)   // rare tail
            atomicAdd(&lhist[(unsigned)(K[i] >> 50)], 1u);
        __syncthreads();

        const uint4* H4 = (const uint4*)lhist;
        uint4 h0 = H4[tid * 4 + 0];
        uint4 h1 = H4[tid * 4 + 1];
        uint4 h2 = H4[tid * 4 + 2];
        uint4 h3 = H4[tid * 4 + 3];
        int L = (int)(h0.x + h0.y + h0.z + h0.w + h1.x + h1.y + h1.z + h1.w +
                      h2.x + h2.y + h2.z + h2.w + h3.x + h3.y + h3.z + h3.w);
        int pfx = L;
        #pragma unroll
        for (int o = 1; o < 64; o <<= 1) {
            int v = __shfl_up(pfx, o);
            if (lane >= o) pfx += v;
        }
        if (lane == 63) wsum[warp] = pfx;
        __syncthreads();
        if (tid == 0) {
            int a = 0;
            for (int w = 0; w < 16; ++w) { int t = wsum[w]; wsum[w] = a; a += t; }
            sTot = a;
        }
        __syncthreads();
        int incl = pfx + wsum[warp];
        int up = sTot - incl;                 // keys in bins owned by higher threads
        if (up < TOPK && up + L >= TOPK) {    // crossing thread (unique)
            unsigned hh[16] = {h0.x, h0.y, h0.z, h0.w, h1.x, h1.y, h1.z, h1.w,
                               h2.x, h2.y, h2.z, h2.w, h3.x, h3.y, h3.z, h3.w};
            int c = up; int tf = 0; int Sv = 0; unsigned htv = 0; int fnd = 0;
            #pragma unroll
            for (int j = 15; j >= 0; --j) {
                int nc = c + (int)hh[j];
                if (!fnd && nc >= TOPK) { tf = j; Sv = c; htv = hh[j]; fnd = 1; }
                c = nc;
            }
            sT = tid * 16 + tf;
            sRemT = TOPK - Sv;
            sHt = (int)htv;
        }
    }
    __syncthreads();

    bool needRadix = false;
    if (cnt >= TOPK && cnt <= CKCAP) {
        int thr = sT, rem = sRemT, ht = sHt;
        if (ht <= TIEK) {
            // ---- fast exact select from registers: one pass + tie-rank ----
            if (tid == 0) { sSel = 0; sTie = 0; }
            __syncthreads();
            #pragma unroll
            for (int r = 0; r < KREGS; ++r) {
                int i = tid + (r << 10);
                ull k2 = kreg[r];
                int bin = (int)(unsigned)(k2 >> 50);
                bool sel = (i < cnt) && (bin > thr);
                bool tie = (i < cnt) && (bin == thr);
                ull bal = __ballot(sel);
                int cw = __popcll(bal);
                if (cw) {
                    int ldr = __ffsll((long long)bal) - 1;
                    int bw = 0;
                    if (lane == ldr) bw = atomicAdd(&sSel, cw);
                    bw = __shfl(bw, ldr);
                    if (sel) sk[bw + __popcll(bal & ((1ull << lane) - 1ull))] = k2;
                }
                ull bal2 = __ballot(tie);
                int cw2 = __popcll(bal2);
                if (cw2) {
                    int ldr = __ffsll((long long)bal2) - 1;
                    int bw = 0;
                    if (lane == ldr) bw = atomicAdd(&sTie, cw2);
                    bw = __shfl(bw, ldr);
                    if (tie) tb[bw + __popcll(bal2 & ((1ull << lane) - 1ull))] = k2;
                }
            }
            for (int i = (KREGS << 10) + tid; i < cnt; i += 1024) {   // rare tail
                ull k2 = K[i];
                int bin = (int)(unsigned)(k2 >> 50);
                bool sel = bin > thr;
                bool tie = bin == thr;
                ull bal = __ballot(sel);
                int cw = __popcll(bal);
                if (cw) {
                    int ldr = __ffsll((long long)bal) - 1;
                    int bw = 0;
                    if (lane == ldr) bw = atomicAdd(&sSel, cw);
                    bw = __shfl(bw, ldr);
                    if (sel) sk[bw + __popcll(bal & ((1ull << lane) - 1ull))] = k2;
                }
                ull bal2 = __ballot(tie);
                int cw2 = __popcll(bal2);
                if (cw2) {
                    int ldr = __ffsll((long long)bal2) - 1;
                    int bw = 0;
                    if (lane == ldr) bw = atomicAdd(&sTie, cw2);
                    bw = __shfl(bw, ldr);
                    if (tie) tb[bw + __popcll(bal2 & ((1ull << lane) - 1ull))] = k2;
                }
            }
            __syncthreads();
            int tieCnt = sTie;                 // == ht
            for (int i = tid; i < tieCnt; i += 1024) {
                ull me = tb[i];
                int rank = 0;
                for (int j = 0; j < tieCnt; ++j) rank += (tb[j] > me);
                if (rank < rem) { int pos = atomicAdd(&sSel, 1); sk[pos] = me; }
            }
            __syncthreads();                   // sk[0..TOPK) complete
        } else {
            needRadix = true;                  // giant tie bin: unreachable
        }
    } else if (cnt >= TOPK) {
        needRadix = true;                      // cnt > CKCAP: unreachable
    }

    if (needRadix) {
        // ---- fallback: 8x8-bit radix select (proven, statically unreachable) ----
        int cntc = cntS;
        ull P = 0; int rem = TOPK;
        for (int pass = 7; pass >= 0; --pass) {
            int sh = pass * 8;
            *reinterpret_cast<uint4*>(&histw[tid * 4]) = make_uint4(0, 0, 0, 0);
            __syncthreads();
            ull pmask = (pass == 7) ? 0ull : (~0ull << (sh + 8));
            unsigned* hw = &histw[warp << 8];
            #pragma unroll
            for (int r = 0; r < KREGS; ++r) {
                int i = tid + (r << 10);
                if (i < cntc && (kreg[r] & pmask) == P)
                    atomicAdd(&hw[(unsigned)(kreg[r] >> sh) & 255u], 1u);
            }
            for (int i = (KREGS << 10) + tid; i < cntc; i += 1024) {
                ull k2 = K[i];
                if ((k2 & pmask) == P)
                    atomicAdd(&hw[(unsigned)(k2 >> sh) & 255u], 1u);
            }
            __syncthreads();
            unsigned x = 0, pfx2 = 0;
            if (tid < 256) {
                int d = 255 - tid;
                #pragma unroll
                for (int w = 0; w < 16; ++w) x += histw[(w << 8) + d];
                pfx2 = x;
                #pragma unroll
                for (int o = 1; o < 64; o <<= 1) {
                    unsigned v = __shfl_up(pfx2, o);
                    if (lane >= o) pfx2 += v;
                }
                if (lane == 63) wtot4[tid >> 6] = pfx2;
            }
            __syncthreads();
            if (tid < 256) {
                int d = 255 - tid;
                int ws2 = tid >> 6;
                unsigned add = 0;
                if (ws2 > 0) add += wtot4[0];
                if (ws2 > 1) add += wtot4[1];
                if (ws2 > 2) add += wtot4[2];
                unsigned pi   = pfx2 + add;
                unsigned excl = pi - x;
                if (x && excl < (unsigned)rem && pi >= (unsigned)rem) {
                    sP = P | ((ull)(unsigned)d << sh);
                    int nr = rem - (int)excl;
                    sRem = nr;
                    sDone = ((int)x == nr) ? 1 : 0;
                }
            }
            __syncthreads();
            P = sP; rem = sRem;
            if (sDone) break;
        }
        if (tid == 0) sCnt = 0;
        __syncthreads();
        #pragma unroll
        for (int r = 0; r < KREGS; ++r) {
            int i = tid + (r << 10);
            bool sel = (i < cntc) && (kreg[r] >= P);
            ull bal = __ballot(sel);
            int cw = __popcll(bal);
            if (cw) {
                int ldr = __ffsll((long long)bal) - 1;
                int bw = 0;
                if (lane == ldr) bw = atomicAdd(&sCnt, cw);
                bw = __shfl(bw, ldr);
                if (sel) {
                    int pos = bw + __popcll(bal & ((1ull << lane) - 1ull));
                    if (pos < TOPK) sk[pos] = kreg[r];
                }
            }
        }
        for (int i = (KREGS << 10) + tid; i < cntc; i += 1024) {
            ull k2 = K[i];
            bool sel = (k2 >= P);
            ull bal = __ballot(sel);
            int cw = __popcll(bal);
            if (cw) {
                int ldr = __ffsll((long long)bal) - 1;
                int bw = 0;
                if (lane == ldr) bw = atomicAdd(&sCnt, cw);
                bw = __shfl(bw, ldr);
                if (sel) {
                    int pos = bw + __popcll(bal & ((1ull << lane) - 1ull));
                    if (pos < TOPK) sk[pos] = k2;
                }
            }
        }
        __syncthreads();
        int fc = sCnt;
        for (int i = fc + tid; i < TOPK; i += 1024) sk[i] = PADKEY;
        __syncthreads();
    } else if (cnt < TOPK) {
        // ---- take all valid + fill with smallest-index invalid (unreachable) ----
        for (int i = tid; i < cnt; i += 1024) sk[i] = K[i];
        int F = TOPK - cnt;
        const ull* V = vbm2 + (size_t)b * NPROP * 2;
        int r0 = 2 * tid, r1 = r0 + 1;
        int v0 = 0, v1 = 0;
        if (r0 < NPROP) v0 = NFG - __popcll(V[r0 * 2]) - __popcll(V[r0 * 2 + 1]);
        if (r1 < NPROP) v1 = NFG - __popcll(V[r1 * 2]) - __popcll(V[r1 * 2 + 1]);
        int s2 = v0 + v1;
        int pfx = s2;
        #pragma unroll
        for (int o = 1; o < 64; o <<= 1) {
            int t = __shfl_up(pfx, o);
            if (lane >= o) pfx += t;
        }
        if (lane == 63) wsum[warp] = pfx;
        __syncthreads();
        if (tid == 0) {
            int a = 0;
            for (int w = 0; w < 16; ++w) { int t = wsum[w]; wsum[w] = a; a += t; }
        }
        __syncthreads();
        int excl = pfx - s2 + wsum[warp];
        if (r0 < NPROP) rex[r0] = excl;
        if (r1 < NPROP) rex[r1] = excl + v0;
        __syncthreads();
        for (int r = tid; r < NPROP; r += 1024) {
            int e = rex[r];
            if (e < F) {
                ull m0 = V[r * 2], m1v = V[r * 2 + 1];
                int rank = e;
                ull inv = ~m0;
                while (inv && rank < F) {
                    int cb = __builtin_ctzll(inv); inv &= inv - 1;
                    unsigned idx = (unsigned)(r * NFG + cb);
                    sk[cnt + rank] = ((ull)ORD_NEG1 << 32) | (ull)(0xFFFFFFFFu - idx);
                    ++rank;
                }
                inv = (~m1v) & ((1ull << 26) - 1ull);
                while (inv && rank < F) {
                    int cb = __builtin_ctzll(inv); inv &= inv - 1;
                    unsigned idx = (unsigned)(r * NFG + 64 + cb);
                    sk[cnt + rank] = ((ull)ORD_NEG1 << 32) | (ull)(0xFFFFFFFFu - idx);
                    ++rank;
                }
            }
        }
        __syncthreads();
    }

    // ---- decode 2048 + class bucketing -> global ----
    float lmax = 0.0f;
    float4 myb[2]; int myl[2]; bool vk2[2]; ull kk2[2];
    #pragma unroll
    for (int r = 0; r < 2; ++r) {
        int pos0 = tid + (r << 10);
        ull k = sk[pos0];
        unsigned idx = 0xFFFFFFFFu - (unsigned)(k & 0xFFFFFFFFu);
        int n2 = (int)(idx / NFG), c2 = (int)(idx % NFG);  // label = c2+1
        int row2 = b * NPROP + n2;
        float4 p  = *reinterpret_cast<const float4*>(props + (size_t)row2 * 4);
        float4 r4 = *reinterpret_cast<const float4*>(
            reg + ((size_t)row2 * NCLS + (c2 + 1)) * 4);
        float4 bxv = decode_clip(p, r4);
        myb[r] = bxv; myl[r] = c2 + 1; kk2[r] = k;
        vk2[r] = (((unsigned)(k >> 32)) != ORD_NEG1);
        lmax = fmaxf(lmax, fmaxf(fmaxf(bxv.x, bxv.y), fmaxf(bxv.z, bxv.w)));
    }
    #pragma unroll
    for (int o = 32; o; o >>= 1) lmax = fmaxf(lmax, __shfl_xor(lmax, o));
    if (lane == 0) sMax[warp] = lmax;
    if (tid < 96) { ccnt[tid] = 0; cplc[tid] = 0; }
    if (tid == 0) sInv = 0;
    __syncthreads();
    if (tid == 0) {
        float v = sMax[0];
        for (int i = 1; i < 16; ++i) v = fmaxf(v, sMax[i]);
        sM1 = __fadd_rn(v, 1.0f);            // jnp.max(cand_boxes) + 1.0
    }
    #pragma unroll
    for (int r = 0; r < 2; ++r)
        if (vk2[r]) atomicAdd(&ccnt[myl[r] - 1], 1);
    __syncthreads();
    if (tid == 0) {
        int a = 0;
        for (int c2 = 0; c2 < NFG; ++c2) { coff[c2] = a; a += ccnt[c2]; }
        sVT = a;
    }
    __syncthreads();
    float m1 = sM1;
    int validTot = sVT;
    #pragma unroll
    for (int r = 0; r < 2; ++r) {
        int slot;
        if (vk2[r]) {
            int cl = myl[r] - 1;
            slot = coff[cl] + atomicAdd(&cplc[cl], 1);
        } else {
            slot = validTot + atomicAdd(&sInv, 1);
        }
        int g2 = b * TOPK + slot;
        float off = __fmul_rn((float)myl[r], m1);
        float4 ob;
        ob.x = __fadd_rn(myb[r].x, off);
        ob.y = __fadd_rn(myb[r].y, off);
        ob.z = __fadd_rn(myb[r].z, off);
        ob.w = __fadd_rn(myb[r].w, off);
        float area = __fmul_rn(__fsub_rn(ob.z, ob.x), __fsub_rn(ob.w, ob.y));
        clsbox[g2] = ob; clsarea[g2] = area; clskey[g2] = kk2[r];
        keepflag[g2] = 0;
    }
    if (tid < NFG) {
        clscnt[b * 96 + tid] = ccnt[tid];
        clsoff[b * 96 + tid] = coff[tid];
    }
}

// ============ kernel N: per-(image,class) key-sort + greedy NMS -> keepflag + kept-hist ============
__global__ __launch_bounds__(64) void kN(const float4* __restrict__ clsbox,
                                         const float* __restrict__ clsarea,
                                         const ull* __restrict__ clskey,
                                         const int* __restrict__ clscnt,
                                         const int* __restrict__ clsoff,
                                         int* __restrict__ keepflag,
                                         unsigned* __restrict__ hist) {
    int bc = blockIdx.x;
    int b = bc / NFG, c = bc - b * NFG;
    int n = clscnt[b * 96 + c];
    if (n <= 0) return;
    if (n > CLSCAP) n = CLSCAP;   // unreachable at observed densities
    int lane = threadIdx.x;
    int base = b * TOPK + clsoff[b * 96 + c];

    if (n <= 64) {
        ull key = (lane < n) ? clskey[base + lane] : (ull)lane;
        int slot = (lane < n) ? (base + lane) : -1;
        #pragma unroll
        for (int k = 2; k <= 64; k <<= 1) {
            #pragma unroll
            for (int j = k >> 1; j > 0; j >>= 1) {
                int pl = lane ^ j;
                ull qk = __shfl(key, pl);
                int qs = __shfl(slot, pl);
                bool desc = ((lane & k) == 0);
                bool lower = ((lane & j) == 0);
                bool km = (desc == lower);
                bool keepown = km ? (key > qk) : (key < qk);
                key = keepown ? key : qk;
                slot = keepown ? slot : qs;
            }
        }
        float4 b0; float a0 = 0.0f;
        if (slot >= 0) { b0 = clsbox[slot]; a0 = clsarea[slot]; }
        ull alive = (n == 64) ? ~0ull : ((1ull << n) - 1ull);
        #pragma unroll 1
        for (int i = 0; i < n; ++i) {
            if (!((alive >> i) & 1ull)) continue;
            float bix = __shfl(b0.x, i), biy = __shfl(b0.y, i);
            float biz = __shfl(b0.z, i), biw = __shfl(b0.w, i);
            float ai2 = __shfl(a0, i);
            bool sup = false;
            if (lane < n && lane > i) {
                float lt0 = fmaxf(bix, b0.x), lt1 = fmaxf(biy, b0.y);
                float rb0 = fminf(biz, b0.z), rb1 = fminf(biw, b0.w);
                float w0 = fmaxf(__fsub_rn(rb0, lt0), 0.0f);
                float w1 = fmaxf(__fsub_rn(rb1, lt1), 0.0f);
                float inter = __fmul_rn(w0, w1);
                if (inter > 0.0f) {
                    float un = __fsub_rn(__fadd_rn(ai2, a0), inter);
                    sup = (__fdiv_rn(inter, un) > NMS_TH);
                }
            }
            alive &= ~__ballot(sup);
        }
        if (lane < n) {
            int kp = (int)((alive >> lane) & 1ull);
            keepflag[slot] = kp;
            if (kp) atomicAdd(&hist[(size_t)b * NBIN + (unsigned)(key >> 50)], 1u);
        }
        return;
    }

    // ---- cold path: 64 < n <= 512 (statistically unreachable) ----
    __shared__ ull  skey[CLSCAP];
    __shared__ int  sslot[CLSCAP];
    __shared__ float4 sbox[CLSCAP];
    __shared__ float  sar[CLSCAP];
    __shared__ ull    smask[CLSCAP * 8];
    __shared__ ull    salive[8];
    for (int t = lane; t < n; t += 64) {
        skey[t] = clskey[base + t];
        sslot[t] = base + t;
    }
    __syncthreads();
    for (int r = 0; r < n - 1; ++r) {
        ull best = 0; int bi = -1;
        for (int t = r + lane; t < n; t += 64)
            if (skey[t] > best) { best = skey[t]; bi = t; }
        #pragma unroll
        for (int o = 32; o; o >>= 1) {
            ull ob = __shfl_xor(best, o);
            int oi = __shfl_xor(bi, o);
            if (ob > best) { best = ob; bi = oi; }
        }
        if (lane == 0 && bi != r) {
            ull tk = skey[r]; skey[r] = skey[bi]; skey[bi] = tk;
            int ts = sslot[r]; sslot[r] = sslot[bi]; sslot[bi] = ts;
        }
        __syncthreads();
    }
    for (int t = lane; t < n; t += 64) {
        sbox[t] = clsbox[sslot[t]];
        sar[t]  = clsarea[sslot[t]];
    }
    __syncthreads();
    int W = (n + 63) >> 6;
    for (int i = lane; i < n; i += 64) {
        float4 a = sbox[i]; float ai = sar[i];
        for (int w = 0; w < W; ++w) {
            ull word = 0;
            int jn = n - (w << 6); if (jn > 64) jn = 64;
            for (int s = 0; s < jn; ++s) {
                int j = (w << 6) + s;
                if (j > i) {
                    float4 cc = sbox[j];
                    float lt0 = fmaxf(a.x, cc.x), lt1 = fmaxf(a.y, cc.y);
                    float rb0 = fminf(a.z, cc.z), rb1 = fminf(a.w, cc.w);
                    float w0 = fmaxf(__fsub_rn(rb0, lt0), 0.0f);
                    float w1 = fmaxf(__fsub_rn(rb1, lt1), 0.0f);
                    float inter = __fmul_rn(w0, w1);
                    if (inter > 0.0f) {
                        float un = __fsub_rn(__fadd_rn(ai, sar[j]), inter);
                        if (__fdiv_rn(inter, un) > NMS_TH) word |= (1ull << s);
                    }
                }
            }
            smask[i * W + w] = word;
        }
    }
    __syncthreads();
    ull alive = 0;
    if (lane < W) {
        int rem = n - (lane << 6);
        alive = (rem >= 64) ? ~0ull : ((1ull << rem) - 1ull);
    }
    for (int i = 0; i < n; ++i) {
        ull aw = __shfl(alive, i >> 6);
        if ((aw >> (i & 63)) & 1ull) {
            if (lane < W) alive &= ~smask[i * W + lane];
        }
    }
    if (lane < W) salive[lane] = alive;
    __syncthreads();
    for (int t = lane; t < n; t += 64) {
        int kp = (int)((salive[t >> 6] >> (t & 63)) & 1ull);
        keepflag[sslot[t]] = kp;
        if (kp) atomicAdd(&hist[(size_t)b * NBIN + (unsigned)(skey[t] >> 50)], 1u);
    }
}

// ============ kernel E: top-100 of kept via kept-histogram (fallback: two-segment radix) ============
__global__ __launch_bounds__(1024) void kE(const int* __restrict__ keepflag,
                                           const ull* __restrict__ clskey,
                                           const unsigned* __restrict__ hist,
                                           const float* __restrict__ reg,
                                           const float* __restrict__ props,
                                           float* __restrict__ out) {
    int b = blockIdx.x;
    int tid = threadIdx.x;
    int lane = tid & 63, warp = tid >> 6;
    __shared__ ull kk[TOPK];
    __shared__ int ks[TOPK];
    __shared__ unsigned histw[16 * 256];
    __shared__ unsigned wtot4[4];
    __shared__ ull sP;
    __shared__ int sRem, sDone, sK, sFC;
    __shared__ int wsum[16];
    __shared__ int sTot, sT, sRemT, sHt;
    __shared__ int sW, sTie;
    __shared__ ull fkey[128];
    __shared__ int fslot[128];
    __shared__ ull tb2[TIEE];
    __shared__ int ts2[TIEE];

    const ull* KY = clskey + (size_t)b * TOPK;
    const int* KF = keepflag + (size_t)b * TOPK;
    const unsigned* H = hist + (size_t)b * NBIN;

    // ---- kept-key histogram scan: total + top-100 threshold ----
    {
        const uint4* H4 = (const uint4*)H;
        uint4 h0 = H4[tid * 4 + 0];
        uint4 h1 = H4[tid * 4 + 1];
        uint4 h2 = H4[tid * 4 + 2];
        uint4 h3 = H4[tid * 4 + 3];
        int L = (int)(h0.x + h0.y + h0.z + h0.w + h1.x + h1.y + h1.z + h1.w +
                      h2.x + h2.y + h2.z + h2.w + h3.x + h3.y + h3.z + h3.w);
        int pfx = L;
        #pragma unroll
        for (int o = 1; o < 64; o <<= 1) {
            int v = __shfl_up(pfx, o);
            if (lane >= o) pfx += v;
        }
        if (lane == 63) wsum[warp] = pfx;
        __syncthreads();
        if (tid == 0) {
            int a = 0;
            for (int w = 0; w < 16; ++w) { int t = wsum[w]; wsum[w] = a; a += t; }
            sTot = a;
        }
        __syncthreads();
        int incl = pfx + wsum[warp];
        int up = sTot - incl;
        if (up < DETS && up + L >= DETS) {
            unsigned hh[16] = {h0.x, h0.y, h0.z, h0.w, h1.x, h1.y, h1.z, h1.w,
                               h2.x, h2.y, h2.z, h2.w, h3.x, h3.y, h3.z, h3.w};
            int c = up; int tf = 0; int Sv = 0; unsigned htv = 0; int fnd = 0;
            #pragma unroll
            for (int j = 15; j >= 0; --j) {
                int nc = c + (int)hh[j];
                if (!fnd && nc >= DETS) { tf = j; Sv = c; htv = hh[j]; fnd = 1; }
                c = nc;
            }
            sT = tid * 16 + tf;
            sRemT = DETS - Sv;
            sHt = (int)htv;
        }
    }
    __syncthreads();

    if (sTot >= DETS && sHt <= TIEE) {
        // ---- fast path: gather winners + tie-rank + sort-128 ----
        int thr = sT, rem = sRemT;
        if (tid == 0) { sW = 0; sTie = 0; }
        __syncthreads();
        for (int s = tid; s < TOPK; s += 1024) {
            int kf = KF[s];
            ull key = KY[s];
            int bin = (int)(unsigned)(key >> 50);
            bool sel = kf && (bin > thr);
            bool tie = kf && (bin == thr);
            ull bal = __ballot(sel);
            int cw = __popcll(bal);
            if (cw) {
                int ldr = __ffsll((long long)bal) - 1;
                int bw = 0;
                if (lane == ldr) bw = atomicAdd(&sW, cw);
                bw = __shfl(bw, ldr);
                if (sel) {
                    int p2 = bw + __popcll(bal & ((1ull << lane) - 1ull));
                    fkey[p2] = key; fslot[p2] = s;
                }
            }
            ull bal2 = __ballot(tie);
            int cw2 = __popcll(bal2);
            if (cw2) {
                int ldr = __ffsll((long long)bal2) - 1;
                int bw = 0;
                if (lane == ldr) bw = atomicAdd(&sTie, cw2);
                bw = __shfl(bw, ldr);
                if (tie) {
                    int p2 = bw + __popcll(bal2 & ((1ull << lane) - 1ull));
                    tb2[p2] = key; ts2[p2] = s;
                }
            }
        }
        __syncthreads();
        int tieCnt = sTie;
        for (int i = tid; i < tieCnt; i += 1024) {
            ull me = tb2[i];
            int rank = 0;
            for (int j = 0; j < tieCnt; ++j) rank += (tb2[j] > me);
            if (rank < rem) {
                int pos = atomicAdd(&sW, 1);
                fkey[pos] = me; fslot[pos] = ts2[i];
            }
        }
        __syncthreads();                       // sW == DETS
        for (int i = DETS + tid; i < 128; i += 1024) { fkey[i] = 0; fslot[i] = -1; }
        __syncthreads();
        if (warp == 0) {
            int base2 = lane * 2;
            ull a = fkey[base2], bb = fkey[base2 + 1];
            int pa = fslot[base2], pb = fslot[base2 + 1];
            #pragma unroll
            for (int k2 = 2; k2 <= 128; k2 <<= 1)
                wl_pair(a, bb, pa, pb, lane, base2, k2,
                        (k2 >> 1) < 64 ? (k2 >> 1) : 64);
            #pragma unroll
            for (int e = 0; e < 2; ++e) {
                int rnk = base2 + e;
                ull kv = e ? bb : a;
                int sl = e ? pb : pa;
                if (rnk < DETS && sl >= 0) {
                    unsigned idx = 0xFFFFFFFFu - (unsigned)(kv & 0xFFFFFFFFu);
                    int n2 = (int)(idx / NFG), c2 = (int)(idx % NFG);
                    int row2 = b * NPROP + n2;
                    float4 pp = *reinterpret_cast<const float4*>(
                        props + (size_t)row2 * 4);
                    float4 r4 = *reinterpret_cast<const float4*>(
                        reg + ((size_t)row2 * NCLS + (c2 + 1)) * 4);
                    float4 bx = decode_clip(pp, r4);
                    *reinterpret_cast<float4*>(
                        out + ((size_t)b * DETS + rnk) * 4) = bx;
                    out[NIMG * DETS * 4 + b * DETS + rnk] = fordinv((unsigned)(kv >> 32));
                    out[NIMG * DETS * 5 + b * DETS + rnk] = (float)(c2 + 1);
                }
            }
        }
        return;
    }

    // ---- fallback: two-segment radix (statistically unreachable) ----
    int emitted = 0;
    #pragma unroll 1
    for (int seg = 0; seg < 2; ++seg) {
        __syncthreads();
        if (tid == 0) sK = 0;
        __syncthreads();
        if (emitted < DETS) {
            for (int s = tid; s < TOPK; s += 1024) {
                bool f = (seg == 0) ? (KF[s] != 0) : (KF[s] == 0);
                ull key = KY[s];
                ull bal = __ballot(f);
                int cw = __popcll(bal);
                if (cw) {
                    int ldr = __ffsll((long long)bal) - 1;
                    int bw = 0;
                    if (lane == ldr) bw = atomicAdd(&sK, cw);
                    bw = __shfl(bw, ldr);
                    if (f) {
                        int p2 = bw + __popcll(bal & ((1ull << lane) - 1ull));
                        kk[p2] = key; ks[p2] = s;
                    }
                }
            }
        }
        __syncthreads();
        int K2 = sK;
        int T = DETS - emitted;
        if (T > K2) T = K2;
        if (emitted < DETS && K2 > 0) {
            ull P = 0;
            if (K2 > T) {
                int rem = T;
                for (int pass = 7; pass >= 0; --pass) {
                    int sh = pass * 8;
                    *reinterpret_cast<uint4*>(&histw[tid * 4]) = make_uint4(0, 0, 0, 0);
                    __syncthreads();
                    ull pmask = (pass == 7) ? 0ull : (~0ull << (sh + 8));
                    unsigned* hw = &histw[warp << 8];
                    for (int i = tid; i < K2; i += 1024) {
                        ull k2 = kk[i];
                        if ((k2 & pmask) == P)
                            atomicAdd(&hw[(unsigned)(k2 >> sh) & 255u], 1u);
                    }
                    __syncthreads();
                    unsigned x = 0, pfx = 0;
                    if (tid < 256) {
                        int d = 255 - tid;
                        #pragma unroll
                        for (int w = 0; w < 16; ++w) x += histw[(w << 8) + d];
                        pfx = x;
                        #pragma unroll
                        for (int o = 1; o < 64; o <<= 1) {
                            unsigned v = __shfl_up(pfx, o);
                            if (lane >= o) pfx += v;
                        }
                        if (lane == 63) wtot4[tid >> 6] = pfx;
                    }
                    __syncthreads();
                    if (tid < 256) {
                        int d = 255 - tid;
                        int ws2 = tid >> 6;
                        unsigned add = 0;
                        if (ws2 > 0) add += wtot4[0];
                        if (ws2 > 1) add += wtot4[1];
                        if (ws2 > 2) add += wtot4[2];
                        unsigned pi   = pfx + add;
                        unsigned excl = pi - x;
                        if (x && excl < (unsigned)rem && pi >= (unsigned)rem) {
                            sP = P | ((ull)(unsigned)d << sh);
                            int nr = rem - (int)excl;
                            sRem = nr;
                            sDone = ((int)x == nr) ? 1 : 0;
                        }
                    }
                    __syncthreads();
                    P = sP; rem = sRem;
                    if (sDone) break;
                }
            }
            if (tid == 0) sFC = 0;
            __syncthreads();
            for (int i = tid; i < K2; i += 1024) {
                ull k2 = kk[i];
                bool sel = (k2 >= P);
                ull bal = __ballot(sel);
                int cw = __popcll(bal);
                if (cw) {
                    int ldr = __ffsll((long long)bal) - 1;
                    int bw = 0;
                    if (lane == ldr) bw = atomicAdd(&sFC, cw);
                    bw = __shfl(bw, ldr);
                    if (sel) {
                        int p2 = bw + __popcll(bal & ((1ull << lane) - 1ull));
                        if (p2 < T) { fkey[p2] = k2; fslot[p2] = ks[i]; }
                    }
                }
            }
            __syncthreads();
            int FC = sFC; if (FC > T) FC = T;
            for (int i = FC + tid; i < 128; i += 1024) { fkey[i] = 0; fslot[i] = -1; }
            __syncthreads();
            if (warp == 0) {
                int base2 = lane * 2;
                ull a = fkey[base2], bb = fkey[base2 + 1];
                int pa = fslot[base2], pb = fslot[base2 + 1];
                #pragma unroll
                for (int k2 = 2; k2 <= 128; k2 <<= 1)
                    wl_pair(a, bb, pa, pb, lane, base2, k2,
                            (k2 >> 1) < 64 ? (k2 >> 1) : 64);
                #pragma unroll
                for (int e = 0; e < 2; ++e) {
                    int rnk = base2 + e;
                    ull kv = e ? bb : a;
                    int sl = e ? pb : pa;
                    if (rnk < T && sl >= 0) {
                        int r2 = emitted + rnk;
                        unsigned idx = 0xFFFFFFFFu - (unsigned)(kv & 0xFFFFFFFFu);
                        int n2 = (int)(idx / NFG), c2 = (int)(idx % NFG);
                        int row2 = b * NPROP + n2;
                        float4 pp = *reinterpret_cast<const float4*>(
                            props + (size_t)row2 * 4);
                        float4 r4 = *reinterpret_cast<const float4*>(
                            reg + ((size_t)row2 * NCLS + (c2 + 1)) * 4);
                        float4 bx = decode_clip(pp, r4);
                        *reinterpret_cast<float4*>(
                            out + ((size_t)b * DETS + r2) * 4) = bx;
                        out[NIMG * DETS * 4 + b * DETS + r2] =
                            (seg == 0) ? fordinv((unsigned)(kv >> 32)) : -1.0f;
                        out[NIMG * DETS * 5 + b * DETS + r2] = (float)(c2 + 1);
                    }
                }
            }
            emitted += T;
        }
        __syncthreads();
    }
}

// ---------------- launch ----------------
extern "C" void kernel_launch(void* const* d_in, const int* in_sizes, int n_in,
                              void* d_out, int out_size, void* d_ws, size_t ws_size,
                              hipStream_t stream) {
    (void)in_sizes; (void)n_in; (void)out_size; (void)ws_size;
    const float* logits = (const float*)d_in[0];   // [16000, 91]
    const float* reg    = (const float*)d_in[1];   // [16000, 364]
    const float* props  = (const float*)d_in[2];   // [8, 2000, 4]
    float* out = (float*)d_out;                    // boxes(3200) | scores(800) | labels(800)
    char* ws = (char*)d_ws;

    int*      cntv   = (int*)(ws + OFF_CNT);
    unsigned* hist   = (unsigned*)(ws + OFF_HIST);
    ull*      vbm2   = (ull*)(ws + OFF_VBM);
    ull*      ck     = (ull*)(ws + OFF_CK);
    float4*   clsbox = (float4*)(ws + OFF_CLSBOX);
    float*    clsar  = (float*)(ws + OFF_CLSAR);
    ull*      clskey = (ull*)(ws + OFF_CLSKEY);
    int*      keepf  = (int*)(ws + OFF_KEEPF);
    int*      clscnt = (int*)(ws + OFF_CLSCNT);
    int*      clsoff = (int*)(ws + OFF_CLSOFF);

    hipMemsetAsync(ws, 0, MEMSET_BYTES, stream);   // cntv + kept-histograms
    hipLaunchKernelGGL(kA, dim3(NROW / 16), dim3(1024), 0, stream,
                       logits, reg, props, ck, cntv, vbm2);
    hipLaunchKernelGGL(kB, dim3(NIMG), dim3(1024), 0, stream,
                       ck, cntv, vbm2, reg, props,
                       clsbox, clsar, clskey, keepf, clscnt, clsoff);
    hipLaunchKernelGGL(kN, dim3(NIMG * NFG), dim3(64), 0, stream,
                       clsbox, clsar, clskey, clscnt, clsoff, keepf, hist);
    hipLaunchKernelGGL(kE, dim3(NIMG), dim3(1024), 0, stream,
                       keepf, clskey, hist, reg, props, out);
}